// Round 1
// baseline (7558.418 us; speedup 1.0000x reference)
//
#include <hip/hip_runtime.h>
#include <hip/hip_bf16.h>
#include <stdint.h>

// Problem constants
#define B_  64
#define S_  512
#define E_  300
#define H_  256
#define T_  (B_*S_)     // 32768 tokens
#define G4H 1024        // 4*H gate rows per direction

using half8  = __attribute__((ext_vector_type(8))) _Float16;
using float4v = __attribute__((ext_vector_type(4))) float;

__device__ inline float sigm(float x) { return 1.f / (1.f + __expf(-x)); }
__device__ inline float tanhf_(float x) {
  float cx = fminf(fmaxf(x, -15.f), 15.f);
  float e = __expf(2.f * cx);
  return (e - 1.f) / (e + 1.f);
}

// ---------------------------------------------------------------------------
// Prep: w_ih -> Bt[n'][k] fp16, rows permuted n' = dir*1024 + 4*j + gate
// (gate-major PyTorch rows g*256+j  ->  interleaved 4j+g), K zero-padded.
// ---------------------------------------------------------------------------
__global__ __launch_bounds__(256) void k_prep_wih(const float* __restrict__ wf,
    const float* __restrict__ wb, _Float16* __restrict__ Bt,
    int KIN, int KP, int total)
{
  int idx = blockIdx.x * 256 + threadIdx.x;
  if (idx >= total) return;
  int n = idx / KP, k = idx % KP;
  int dd = n >> 10, nn = n & 1023;
  int row = (nn & 3) * 256 + (nn >> 2);
  const float* src = dd ? wb : wf;
  Bt[idx] = (_Float16)(k < KIN ? src[row * KIN + k] : 0.f);
}

// w_hh -> Wr[d][n'][k] fp16, same row permutation
__global__ __launch_bounds__(256) void k_prep_whh(const float* __restrict__ wf,
    const float* __restrict__ wb, _Float16* __restrict__ Wr)
{
  int idx = blockIdx.x * 256 + threadIdx.x;     // 0 .. 2*1024*256-1
  int dd = idx >> 18;
  int rem = idx & 262143;
  int n = rem >> 8, k = rem & 255;
  int row = (n & 3) * 256 + (n >> 2);
  Wr[idx] = (_Float16)((dd ? wb : wf)[row * 256 + k]);
}

// combined bias (b_ih + b_hh), permuted, fp32 [2][1024]
__global__ void k_prep_bias(const float* __restrict__ bif, const float* __restrict__ bhf,
    const float* __restrict__ bib, const float* __restrict__ bhb, float* __restrict__ bias)
{
  int n = blockIdx.x * 256 + threadIdx.x;       // 0..2047
  int dd = n >> 10, nn = n & 1023;
  int row = (nn & 3) * 256 + (nn >> 2);
  bias[n] = dd ? (bib[row] + bhb[row]) : (bif[row] + bhf[row]);
}

// embedding gather -> xbf fp16 [T][320], token t = s*64+b, k>=300 zero
__global__ __launch_bounds__(256) void k_gather(const int* __restrict__ ids,
    const float* __restrict__ emb, _Float16* __restrict__ xbf)
{
  int idx = blockIdx.x * 256 + threadIdx.x;     // T*40 threads, 8 f16 each
  int tt = idx / 40;
  int ch = idx % 40;
  int b = tt & 63, s = tt >> 6;
  int id = ids[b * S_ + s];
  const float* src = emb + (size_t)id * E_ + ch * 8;
  half8 v;
#pragma unroll
  for (int e = 0; e < 8; ++e) {
    int k = ch * 8 + e;
    v[e] = (_Float16)(k < E_ ? src[e] : 0.f);
  }
  *(half8*)(xbf + (size_t)tt * 320 + ch * 8) = v;
}

// ---------------------------------------------------------------------------
// Projection GEMM: gx[d][t][b][n'] = A[token][k] * Bt[n'][k] + bias[n']
// f16 MFMA 16x16x32, fp32 accum, 128x128 block tile, BK=64, +8 f16 LDS pad.
// token index of A row == s*64+b  ->  writes land directly in gx layout.
// ---------------------------------------------------------------------------
template<int K>
__global__ __launch_bounds__(256) void k_gemm(const _Float16* __restrict__ A,
    const _Float16* __restrict__ Bt, const float* __restrict__ bias,
    _Float16* __restrict__ gx)
{
  __shared__ _Float16 sA[128 * 72];
  __shared__ _Float16 sB[128 * 72];
  const int tid = threadIdx.x;
  const int t0 = blockIdx.y * 128;
  const int n0 = blockIdx.x * 128;
  const int lane = tid & 63, wid = tid >> 6;
  const int l15 = lane & 15, q = lane >> 4;
  const int wm = wid & 1, wn = wid >> 1;

  float4v acc[4][4] = {};

  for (int kt = 0; kt < K / 64; ++kt) {
    __syncthreads();
#pragma unroll
    for (int c = 0; c < 4; ++c) {
      int f = tid * 4 + c;                 // 0..1023
      int row = f >> 3, seg = f & 7;
      *(half8*)&sA[row * 72 + seg * 8] =
          *(const half8*)(A + (size_t)(t0 + row) * K + kt * 64 + seg * 8);
      *(half8*)&sB[row * 72 + seg * 8] =
          *(const half8*)(Bt + (size_t)(n0 + row) * K + kt * 64 + seg * 8);
    }
    __syncthreads();
#pragma unroll
    for (int kk = 0; kk < 2; ++kk) {
      half8 a[4], b[4];
#pragma unroll
      for (int mt = 0; mt < 4; ++mt)
        a[mt] = *(const half8*)&sA[(wm * 64 + mt * 16 + l15) * 72 + kk * 32 + q * 8];
#pragma unroll
      for (int nt = 0; nt < 4; ++nt)
        b[nt] = *(const half8*)&sB[(wn * 64 + nt * 16 + l15) * 72 + kk * 32 + q * 8];
#pragma unroll
      for (int mt = 0; mt < 4; ++mt)
#pragma unroll
        for (int nt = 0; nt < 4; ++nt)
          acc[mt][nt] = __builtin_amdgcn_mfma_f32_16x16x32_f16(a[mt], b[nt], acc[mt][nt], 0, 0, 0);
    }
  }

#pragma unroll
  for (int mt = 0; mt < 4; ++mt) {
#pragma unroll
    for (int nt = 0; nt < 4; ++nt) {
      int token = t0 + wm * 64 + mt * 16 + q * 4;
      int n = n0 + wn * 64 + nt * 16 + l15;
      float bs = bias[n];
      size_t base = (size_t)(n >> 10) * ((size_t)T_ * G4H) + (size_t)token * G4H + (n & 1023);
#pragma unroll
      for (int r = 0; r < 4; ++r)
        gx[base + (size_t)r * G4H] = (_Float16)(acc[mt][nt][r] + bs);
    }
  }
}

// ---------------------------------------------------------------------------
// One recurrent step, both directions (blockIdx.z = dir).
// Block: 32 batch x 64 gate-rows (16 h-indices). f16 MFMA, fp32 cell state.
// grid (16, 2, 2), 256 threads.
// ---------------------------------------------------------------------------
template<int LAYER>
__global__ __launch_bounds__(256) void k_step(const _Float16* __restrict__ gx,
    const _Float16* __restrict__ Wr, _Float16* __restrict__ hping,
    float* __restrict__ cst, _Float16* __restrict__ h1bf,
    float* __restrict__ pd, const float* __restrict__ w_lin, int t)
{
  const int d = blockIdx.z;
  const int time = d ? (S_ - 1 - t) : t;
  const int tid = threadIdx.x;
  const int lane = tid & 63, wid = tid >> 6;
  const int l15 = lane & 15, q = lane >> 4;
  const int wm = wid & 1, wn = wid >> 1;
  const int b0 = blockIdx.y * 32 + wm * 16;
  const int n0 = blockIdx.x * 64 + wn * 32;

  const _Float16* hprev = hping + ((size_t)((t & 1) * 2 + d)) * (B_ * H_);
  _Float16*       hnext = hping + ((size_t)(((t + 1) & 1) * 2 + d)) * (B_ * H_);

  float4v acc[2] = {};
#pragma unroll
  for (int kt = 0; kt < 8; ++kt) {
    half8 a = *(const half8*)(hprev + (size_t)(b0 + l15) * H_ + kt * 32 + q * 8);
#pragma unroll
    for (int nt = 0; nt < 2; ++nt) {
      half8 b = *(const half8*)(Wr + (size_t)(d * G4H + n0 + nt * 16 + l15) * H_ + kt * 32 + q * 8);
      acc[nt] = __builtin_amdgcn_mfma_f32_16x16x32_f16(a, b, acc[nt], 0, 0, 0);
    }
  }

  __shared__ float pre[32 * 64];         // [b_local][row_local]
#pragma unroll
  for (int nt = 0; nt < 2; ++nt)
#pragma unroll
    for (int r = 0; r < 4; ++r)
      pre[(wm * 16 + q * 4 + r) * 64 + wn * 32 + nt * 16 + l15] = acc[nt][r];
  __syncthreads();

#pragma unroll
  for (int c2 = 0; c2 < 2; ++c2) {
    int cc = tid + c2 * 256;
    int bl = cc >> 4;                    // 0..31
    int jl = cc & 15;                    // 0..15
    int bg = blockIdx.y * 32 + bl;
    int jg = blockIdx.x * 16 + jl;
    float4v p = *(const float4v*)&pre[bl * 64 + jl * 4];
    const _Float16* gxp = gx + ((size_t)d * T_ + (size_t)time * B_ + bg) * G4H
                             + blockIdx.x * 64 + jl * 4;
    float gi = p[0] + (float)gxp[0];
    float gf = p[1] + (float)gxp[1];
    float gg = p[2] + (float)gxp[2];
    float go = p[3] + (float)gxp[3];
    float* cptr = cst + ((size_t)d * B_ + bg) * H_ + jg;
    float cv = sigm(gf) * (*cptr) + sigm(gi) * tanhf_(gg);
    float hv = sigm(go) * tanhf_(cv);
    *cptr = cv;
    hnext[(size_t)bg * H_ + jg] = (_Float16)hv;
    if (LAYER == 0) {
      h1bf[((size_t)time * B_ + bg) * 512 + d * H_ + jg] = (_Float16)hv;
    } else {
      float contrib = 0.5f * hv * w_lin[jg];
      contrib += __shfl_xor(contrib, 1);
      contrib += __shfl_xor(contrib, 2);
      contrib += __shfl_xor(contrib, 4);
      contrib += __shfl_xor(contrib, 8);
      if ((lane & 15) == 0)
        atomicAdd(&pd[(size_t)bg * S_ + time], contrib);
    }
  }
}

// scores + masked-MSE loss
__global__ __launch_bounds__(256) void k_final(const float* __restrict__ pd,
    const float* __restrict__ labels, const int* __restrict__ masks,
    const float* __restrict__ b_lin, float* __restrict__ out)
{
  int b = blockIdx.x;
  int tid = threadIdx.x;
  float bl = b_lin[0];
  float se = 0.f, sm = 0.f;
  for (int s = tid; s < S_; s += 256) {
    float sc = sigm(pd[b * S_ + s] + bl);
    out[b * S_ + s] = sc;
    float m = (float)masks[b * S_ + s];
    float e = sc - labels[b * S_ + s];
    se += e * e * m;
    sm += m;
  }
  for (int off = 1; off < 64; off <<= 1) {
    se += __shfl_xor(se, off);
    sm += __shfl_xor(sm, off);
  }
  __shared__ float rs[4], rm[4];
  int wid = tid >> 6;
  if ((tid & 63) == 0) { rs[wid] = se; rm[wid] = sm; }
  __syncthreads();
  if (tid == 0) {
    float te = 0.f, tm = 0.f;
    for (int w = 0; w < 4; ++w) { te += rs[w]; tm += rm[w]; }
    atomicAdd(out + T_, (te / tm) * (1.f / 64.f));
  }
}

// ---------------------------------------------------------------------------
extern "C" void kernel_launch(void* const* d_in, const int* in_sizes, int n_in,
                              void* d_out, int out_size, void* d_ws, size_t ws_size,
                              hipStream_t stream)
{
  (void)in_sizes; (void)n_in; (void)out_size; (void)ws_size;
  const int*   ids    = (const int*)d_in[0];
  const float* labels = (const float*)d_in[1];
  const int*   masks  = (const int*)d_in[2];
  const float* emb    = (const float*)d_in[3];
  const float* w_ih_0f = (const float*)d_in[4];
  const float* w_hh_0f = (const float*)d_in[5];
  const float* b_ih_0f = (const float*)d_in[6];
  const float* b_hh_0f = (const float*)d_in[7];
  const float* w_ih_0b = (const float*)d_in[8];
  const float* w_hh_0b = (const float*)d_in[9];
  const float* b_ih_0b = (const float*)d_in[10];
  const float* b_hh_0b = (const float*)d_in[11];
  const float* w_ih_1f = (const float*)d_in[12];
  const float* w_hh_1f = (const float*)d_in[13];
  const float* b_ih_1f = (const float*)d_in[14];
  const float* b_hh_1f = (const float*)d_in[15];
  const float* w_ih_1b = (const float*)d_in[16];
  const float* w_hh_1b = (const float*)d_in[17];
  const float* b_ih_1b = (const float*)d_in[18];
  const float* b_hh_1b = (const float*)d_in[19];
  const float* w_lin   = (const float*)d_in[20];
  const float* b_lin   = (const float*)d_in[21];
  float* out = (float*)d_out;

  char* ws = (char*)d_ws;
  size_t off = 0;
  auto alloc = [&](size_t bytes) -> char* {
    char* p = ws + off;
    off += (bytes + 255) & ~(size_t)255;
    return p;
  };
  _Float16* xbf   = (_Float16*)alloc((size_t)T_ * 320 * 2);        // 21 MB
  _Float16* h1bf  = (_Float16*)alloc((size_t)T_ * 512 * 2);        // 33.5 MB
  _Float16* gx    = (_Float16*)alloc((size_t)2 * T_ * G4H * 2);    // 134 MB (reused per layer)
  _Float16* Bt0   = (_Float16*)alloc((size_t)2048 * 320 * 2);
  _Float16* Bt1   = (_Float16*)alloc((size_t)2048 * 512 * 2);
  _Float16* Wr0   = (_Float16*)alloc((size_t)2 * G4H * H_ * 2);
  _Float16* Wr1   = (_Float16*)alloc((size_t)2 * G4H * H_ * 2);
  float*    bias0 = (float*)alloc(2048 * 4);
  float*    bias1 = (float*)alloc(2048 * 4);
  float*    cst   = (float*)alloc((size_t)2 * B_ * H_ * 4);
  _Float16* hping = (_Float16*)alloc((size_t)2 * 2 * B_ * H_ * 2);
  float*    pd    = (float*)alloc((size_t)B_ * S_ * 4);

  // one-time-per-call prep (inputs are re-poisoned in ws each call)
  k_prep_wih<<<(2048 * 320) / 256, 256, 0, stream>>>(w_ih_0f, w_ih_0b, Bt0, 300, 320, 2048 * 320);
  k_prep_wih<<<(2048 * 512) / 256, 256, 0, stream>>>(w_ih_1f, w_ih_1b, Bt1, 512, 512, 2048 * 512);
  k_prep_whh<<<524288 / 256, 256, 0, stream>>>(w_hh_0f, w_hh_0b, Wr0);
  k_prep_whh<<<524288 / 256, 256, 0, stream>>>(w_hh_1f, w_hh_1b, Wr1);
  k_prep_bias<<<8, 256, 0, stream>>>(b_ih_0f, b_hh_0f, b_ih_0b, b_hh_0b, bias0);
  k_prep_bias<<<8, 256, 0, stream>>>(b_ih_1f, b_hh_1f, b_ih_1b, b_hh_1b, bias1);
  k_gather<<<(T_ * 40) / 256, 256, 0, stream>>>(ids, emb, xbf);

  hipMemsetAsync(cst, 0, (size_t)2 * B_ * H_ * 4, stream);
  hipMemsetAsync(hping, 0, (size_t)2 * 2 * B_ * H_ * 2, stream);
  hipMemsetAsync(pd, 0, (size_t)B_ * S_ * 4, stream);
  hipMemsetAsync((char*)d_out + (size_t)T_ * 4, 0, 4, stream);

  // layer 0
  k_gemm<320><<<dim3(16, 256), 256, 0, stream>>>(xbf, Bt0, bias0, gx);
  for (int t = 0; t < S_; ++t)
    k_step<0><<<dim3(16, 2, 2), 256, 0, stream>>>(gx, Wr0, hping, cst, h1bf, pd, w_lin, t);

  // layer 1
  hipMemsetAsync(cst, 0, (size_t)2 * B_ * H_ * 4, stream);
  hipMemsetAsync(hping, 0, (size_t)2 * 2 * B_ * H_ * 2, stream);
  k_gemm<512><<<dim3(16, 256), 256, 0, stream>>>(h1bf, Bt1, bias1, gx);
  for (int t = 0; t < S_; ++t)
    k_step<1><<<dim3(16, 2, 2), 256, 0, stream>>>(gx, Wr1, hping, cst, h1bf, pd, w_lin, t);

  k_final<<<64, 256, 0, stream>>>(pd, labels, masks, b_lin, out);
}

// Round 2
// 5784.665 us; speedup vs baseline: 1.3066x; 1.3066x over previous
//
#include <hip/hip_runtime.h>
#include <hip/hip_bf16.h>
#include <stdint.h>

// Problem constants
#define B_  64
#define S_  512
#define E_  300
#define H_  256
#define T_  (B_*S_)     // 32768 tokens
#define G4H 1024        // 4*H gate rows per direction

using half8  = __attribute__((ext_vector_type(8))) _Float16;
using half4  = __attribute__((ext_vector_type(4))) _Float16;
using float4v = __attribute__((ext_vector_type(4))) float;

__device__ inline float sigm(float x) { return 1.f / (1.f + __expf(-x)); }
__device__ inline float tanhf_(float x) {
  float cx = fminf(fmaxf(x, -15.f), 15.f);
  float e = __expf(2.f * cx);
  return (e - 1.f) / (e + 1.f);
}

// ---------------------------------------------------------------------------
// Prep: w_ih -> Bt[n'][k] fp16, rows permuted n' = dir*1024 + 4*j + gate
// ---------------------------------------------------------------------------
__global__ __launch_bounds__(256) void k_prep_wih(const float* __restrict__ wf,
    const float* __restrict__ wb, _Float16* __restrict__ Bt,
    int KIN, int KP, int total)
{
  int idx = blockIdx.x * 256 + threadIdx.x;
  if (idx >= total) return;
  int n = idx / KP, k = idx % KP;
  int dd = n >> 10, nn = n & 1023;
  int row = (nn & 3) * 256 + (nn >> 2);
  const float* src = dd ? wb : wf;
  Bt[idx] = (_Float16)(k < KIN ? src[row * KIN + k] : 0.f);
}

__global__ __launch_bounds__(256) void k_prep_whh(const float* __restrict__ wf,
    const float* __restrict__ wb, _Float16* __restrict__ Wr)
{
  int idx = blockIdx.x * 256 + threadIdx.x;     // 0 .. 2*1024*256-1
  int dd = idx >> 18;
  int rem = idx & 262143;
  int n = rem >> 8, k = rem & 255;
  int row = (n & 3) * 256 + (n >> 2);
  Wr[idx] = (_Float16)((dd ? wb : wf)[row * 256 + k]);
}

__global__ void k_prep_bias(const float* __restrict__ bif, const float* __restrict__ bhf,
    const float* __restrict__ bib, const float* __restrict__ bhb, float* __restrict__ bias)
{
  int n = blockIdx.x * 256 + threadIdx.x;       // 0..2047
  int dd = n >> 10, nn = n & 1023;
  int row = (nn & 3) * 256 + (nn >> 2);
  bias[n] = dd ? (bib[row] + bhb[row]) : (bif[row] + bhf[row]);
}

__global__ __launch_bounds__(256) void k_gather(const int* __restrict__ ids,
    const float* __restrict__ emb, _Float16* __restrict__ xbf)
{
  int idx = blockIdx.x * 256 + threadIdx.x;     // T*40 threads, 8 f16 each
  int tt = idx / 40;
  int ch = idx % 40;
  int b = tt & 63, s = tt >> 6;
  int id = ids[b * S_ + s];
  const float* src = emb + (size_t)id * E_ + ch * 8;
  half8 v;
#pragma unroll
  for (int e = 0; e < 8; ++e) {
    int k = ch * 8 + e;
    v[e] = (_Float16)(k < E_ ? src[e] : 0.f);
  }
  *(half8*)(xbf + (size_t)tt * 320 + ch * 8) = v;
}

// ---------------------------------------------------------------------------
// Projection GEMM (unchanged from R1): gx[d][t][b][n'] = A @ Bt^T + bias
// ---------------------------------------------------------------------------
template<int K>
__global__ __launch_bounds__(256) void k_gemm(const _Float16* __restrict__ A,
    const _Float16* __restrict__ Bt, const float* __restrict__ bias,
    _Float16* __restrict__ gx)
{
  __shared__ _Float16 sA[128 * 72];
  __shared__ _Float16 sB[128 * 72];
  const int tid = threadIdx.x;
  const int t0 = blockIdx.y * 128;
  const int n0 = blockIdx.x * 128;
  const int lane = tid & 63, wid = tid >> 6;
  const int l15 = lane & 15, q = lane >> 4;
  const int wm = wid & 1, wn = wid >> 1;

  float4v acc[4][4] = {};

  for (int kt = 0; kt < K / 64; ++kt) {
    __syncthreads();
#pragma unroll
    for (int c = 0; c < 4; ++c) {
      int f = tid * 4 + c;
      int row = f >> 3, seg = f & 7;
      *(half8*)&sA[row * 72 + seg * 8] =
          *(const half8*)(A + (size_t)(t0 + row) * K + kt * 64 + seg * 8);
      *(half8*)&sB[row * 72 + seg * 8] =
          *(const half8*)(Bt + (size_t)(n0 + row) * K + kt * 64 + seg * 8);
    }
    __syncthreads();
#pragma unroll
    for (int kk = 0; kk < 2; ++kk) {
      half8 a[4], b[4];
#pragma unroll
      for (int mt = 0; mt < 4; ++mt)
        a[mt] = *(const half8*)&sA[(wm * 64 + mt * 16 + l15) * 72 + kk * 32 + q * 8];
#pragma unroll
      for (int nt = 0; nt < 4; ++nt)
        b[nt] = *(const half8*)&sB[(wn * 64 + nt * 16 + l15) * 72 + kk * 32 + q * 8];
#pragma unroll
      for (int mt = 0; mt < 4; ++mt)
#pragma unroll
        for (int nt = 0; nt < 4; ++nt)
          acc[mt][nt] = __builtin_amdgcn_mfma_f32_16x16x32_f16(a[mt], b[nt], acc[mt][nt], 0, 0, 0);
    }
  }

#pragma unroll
  for (int mt = 0; mt < 4; ++mt) {
#pragma unroll
    for (int nt = 0; nt < 4; ++nt) {
      int token = t0 + wm * 64 + mt * 16 + q * 4;
      int n = n0 + wn * 64 + nt * 16 + l15;
      float bs = bias[n];
      size_t base = (size_t)(n >> 10) * ((size_t)T_ * G4H) + (size_t)token * G4H + (n & 1023);
#pragma unroll
      for (int r = 0; r < 4; ++r)
        gx[base + (size_t)r * G4H] = (_Float16)(acc[mt][nt][r] + bs);
    }
  }
}

// ---------------------------------------------------------------------------
// Persistent recurrence. Grid = 32 blocks: bx = d*16 + rg*4 + g.
//   d  = direction (2)
//   rg = gate-row group: rows [rg*256, rg*256+256) of the 1024 (=> j in [rg*64, rg*64+64))
//   g  = batch group: batches [g*16, g*16+16)
// w_hh quarter lives in VGPRs (128/lane). Cell state in registers (4 cells/thread).
// h exchanged among the 4 rg-blocks of a (d,g) via global ping-pong + device-scope
// counter: producers threadfence + release-add; consumer thread0 acquire-polls.
// ---------------------------------------------------------------------------
template<int LAYER>
__global__ __launch_bounds__(256, 1) void k_rec(const _Float16* __restrict__ gx,
    const _Float16* __restrict__ Wr, _Float16* __restrict__ hglob,
    int* __restrict__ cnt, _Float16* __restrict__ h1bf,
    float* __restrict__ pd2, const float* __restrict__ w_lin)
{
  const int bx = blockIdx.x;
  const int d = bx >> 4, rg = (bx >> 2) & 3, g = bx & 3;
  const int tid = threadIdx.x;
  const int lane = tid & 63, wv = tid >> 6;
  const int l15 = lane & 15, q = lane >> 4;
  const int b0g = g * 16;           // global batch base
  const int n0g = rg * 256;         // gate-row base within direction

  __shared__ _Float16 hstage[16 * 264];   // h_prev [b][k], +8 pad
  __shared__ float    preS[16 * 260];     // preact [b][row_local], +4 pad

  // ---- load this wave's weight fragments into registers (held across t) ----
  half8 wfrag[4][8];
#pragma unroll
  for (int nt = 0; nt < 4; ++nt)
#pragma unroll
    for (int kt = 0; kt < 8; ++kt)
      wfrag[nt][kt] = *(const half8*)(Wr +
          (size_t)(d * G4H + n0g + wv * 64 + nt * 16 + l15) * H_ + kt * 32 + q * 8);

  // epilogue-role constants: thread owns 4 cells (batch bl, j = jbase..jbase+3)
  const int bl = tid >> 4;                  // 0..15
  const int jl4 = (tid & 15) * 4;           // 0..60 (local j within rg's 64)
  const int bglob = b0g + bl;
  const int jg = rg * 64 + jl4;             // global j base of this thread
  float wl[4];
#pragma unroll
  for (int cc = 0; cc < 4; ++cc) wl[cc] = w_lin[jg + cc];
  float creg[4] = {0.f, 0.f, 0.f, 0.f};     // cell state, registers

  int* cflag = cnt + (d * 4 + g);
  _Float16* hbase = hglob + (size_t)((d * 4 + g) * 2) * (16 * 256);

  for (int t = 0; t < S_; ++t) {
    const int time = d ? (S_ - 1 - t) : t;

    // issue gx loads early (independent of flag) — 16 f16 in epilogue layout
    const _Float16* gxp = gx + ((size_t)d * T_ + (size_t)time * B_ + bglob) * G4H
                             + n0g + (tid & 15) * 16;
    half8 gxa = *(const half8*)(gxp);
    half8 gxb = *(const half8*)(gxp + 8);

    // wait for all 4 rg-blocks of (d,g) to have published h(t)
    if (t > 0) {
      if (tid == 0) {
        while (__hip_atomic_load(cflag, __ATOMIC_ACQUIRE, __HIP_MEMORY_SCOPE_AGENT) < 4 * t)
          __builtin_amdgcn_s_sleep(1);
      }
      __syncthreads();
    }

    // stage h(t) [16 x 256] f16 from global ping-pong slot (t&1) into LDS
    {
      const _Float16* hsrc = hbase + (size_t)(t & 1) * (16 * 256);
      int sb = tid >> 4, seg = tid & 15;    // 32B per thread
      half8 v0 = *(const half8*)(hsrc + sb * 256 + seg * 16);
      half8 v1 = *(const half8*)(hsrc + sb * 256 + seg * 16 + 8);
      *(half8*)&hstage[sb * 264 + seg * 16] = v0;
      *(half8*)&hstage[sb * 264 + seg * 16 + 8] = v1;
    }
    __syncthreads();

    // MFMA: pre[b 16][rows 256] += h(t) @ Wq^T   (acc zeroed per step)
    float4v acc[4] = {};
#pragma unroll
    for (int kt = 0; kt < 8; ++kt) {
      half8 a = *(const half8*)&hstage[l15 * 264 + kt * 32 + q * 8];
#pragma unroll
      for (int nt = 0; nt < 4; ++nt)
        acc[nt] = __builtin_amdgcn_mfma_f32_16x16x32_f16(a, wfrag[nt][kt], acc[nt], 0, 0, 0);
    }

    // scatter acc -> preS  (b = q*4+r, row_local = wv*64 + nt*16 + l15)
#pragma unroll
    for (int nt = 0; nt < 4; ++nt)
#pragma unroll
      for (int r = 0; r < 4; ++r)
        preS[(q * 4 + r) * 260 + wv * 64 + nt * 16 + l15] = acc[nt][r];
    __syncthreads();

    // cell update: 4 cells per thread
    half4 hv4;
    float partial = 0.f;
#pragma unroll
    for (int cc = 0; cc < 4; ++cc) {
      float4v p = *(const float4v*)&preS[bl * 260 + (jl4 + cc) * 4];
      float gxi = (float)(cc < 2 ? gxa[cc * 4 + 0] : gxb[(cc - 2) * 4 + 0]);
      float gxf = (float)(cc < 2 ? gxa[cc * 4 + 1] : gxb[(cc - 2) * 4 + 1]);
      float gxg = (float)(cc < 2 ? gxa[cc * 4 + 2] : gxb[(cc - 2) * 4 + 2]);
      float gxo = (float)(cc < 2 ? gxa[cc * 4 + 3] : gxb[(cc - 2) * 4 + 3]);
      float gi = p[0] + gxi, gf = p[1] + gxf, gg = p[2] + gxg, go = p[3] + gxo;
      float cv = sigm(gf) * creg[cc] + sigm(gi) * tanhf_(gg);
      float hv = sigm(go) * tanhf_(cv);
      creg[cc] = cv;
      hv4[cc] = (_Float16)hv;
      if (LAYER == 1) partial += 0.5f * hv * wl[cc];
    }

    // publish h(t+1) quarter to ping-pong slot ((t+1)&1)
    _Float16* hdst = hbase + (size_t)((t + 1) & 1) * (16 * 256);
    *(half4*)(hdst + bl * 256 + jg) = hv4;

    if (LAYER == 0) {
      *(half4*)(h1bf + ((size_t)time * B_ + bglob) * 512 + d * H_ + jg) = hv4;
    } else {
      // reduce 16 threads sharing batch bl (lanes {b*16..b*16+15} within wave)
      partial += __shfl_xor(partial, 1);
      partial += __shfl_xor(partial, 2);
      partial += __shfl_xor(partial, 4);
      partial += __shfl_xor(partial, 8);
      if ((tid & 15) == 0)
        atomicAdd(pd2 + ((size_t)d * B_ + bglob) * S_ + time, partial);
    }

    __threadfence();
    __syncthreads();
    if (tid == 0)
      __hip_atomic_fetch_add(cflag, 1, __ATOMIC_RELEASE, __HIP_MEMORY_SCOPE_AGENT);
  }
}

// scores + masked-MSE loss
__global__ __launch_bounds__(256) void k_final(const float* __restrict__ pd2,
    const float* __restrict__ labels, const int* __restrict__ masks,
    const float* __restrict__ b_lin, float* __restrict__ out)
{
  int b = blockIdx.x;
  int tid = threadIdx.x;
  float bl = b_lin[0];
  float se = 0.f, sm = 0.f;
  for (int s = tid; s < S_; s += 256) {
    float p = pd2[(size_t)b * S_ + s] + pd2[(size_t)(B_ + b) * S_ + s];
    float sc = sigm(p + bl);
    out[b * S_ + s] = sc;
    float m = (float)masks[b * S_ + s];
    float e = sc - labels[b * S_ + s];
    se += e * e * m;
    sm += m;
  }
  for (int off = 1; off < 64; off <<= 1) {
    se += __shfl_xor(se, off);
    sm += __shfl_xor(sm, off);
  }
  __shared__ float rs[4], rm[4];
  int wid = tid >> 6;
  if ((tid & 63) == 0) { rs[wid] = se; rm[wid] = sm; }
  __syncthreads();
  if (tid == 0) {
    float te = 0.f, tm = 0.f;
    for (int w = 0; w < 4; ++w) { te += rs[w]; tm += rm[w]; }
    atomicAdd(out + T_, (te / tm) * (1.f / 64.f));
  }
}

// ---------------------------------------------------------------------------
extern "C" void kernel_launch(void* const* d_in, const int* in_sizes, int n_in,
                              void* d_out, int out_size, void* d_ws, size_t ws_size,
                              hipStream_t stream)
{
  (void)in_sizes; (void)n_in; (void)out_size; (void)ws_size;
  const int*   ids    = (const int*)d_in[0];
  const float* labels = (const float*)d_in[1];
  const int*   masks  = (const int*)d_in[2];
  const float* emb    = (const float*)d_in[3];
  const float* w_ih_0f = (const float*)d_in[4];
  const float* w_hh_0f = (const float*)d_in[5];
  const float* b_ih_0f = (const float*)d_in[6];
  const float* b_hh_0f = (const float*)d_in[7];
  const float* w_ih_0b = (const float*)d_in[8];
  const float* w_hh_0b = (const float*)d_in[9];
  const float* b_ih_0b = (const float*)d_in[10];
  const float* b_hh_0b = (const float*)d_in[11];
  const float* w_ih_1f = (const float*)d_in[12];
  const float* w_hh_1f = (const float*)d_in[13];
  const float* b_ih_1f = (const float*)d_in[14];
  const float* b_hh_1f = (const float*)d_in[15];
  const float* w_ih_1b = (const float*)d_in[16];
  const float* w_hh_1b = (const float*)d_in[17];
  const float* b_ih_1b = (const float*)d_in[18];
  const float* b_hh_1b = (const float*)d_in[19];
  const float* w_lin   = (const float*)d_in[20];
  const float* b_lin   = (const float*)d_in[21];
  float* out = (float*)d_out;

  char* ws = (char*)d_ws;
  size_t off = 0;
  auto alloc = [&](size_t bytes) -> char* {
    char* p = ws + off;
    off += (bytes + 255) & ~(size_t)255;
    return p;
  };
  _Float16* xbf   = (_Float16*)alloc((size_t)T_ * 320 * 2);        // 21 MB
  _Float16* h1bf  = (_Float16*)alloc((size_t)T_ * 512 * 2);        // 33.5 MB
  _Float16* gx    = (_Float16*)alloc((size_t)2 * T_ * G4H * 2);    // 134 MB
  _Float16* Bt0   = (_Float16*)alloc((size_t)2048 * 320 * 2);
  _Float16* Bt1   = (_Float16*)alloc((size_t)2048 * 512 * 2);
  _Float16* Wr0   = (_Float16*)alloc((size_t)2 * G4H * H_ * 2);
  _Float16* Wr1   = (_Float16*)alloc((size_t)2 * G4H * H_ * 2);
  float*    bias0 = (float*)alloc(2048 * 4);
  float*    bias1 = (float*)alloc(2048 * 4);
  _Float16* hg0   = (_Float16*)alloc((size_t)8 * 2 * 16 * 256 * 2); // 128 KB
  _Float16* hg1   = (_Float16*)alloc((size_t)8 * 2 * 16 * 256 * 2); // 128 KB
  int*      cnt0  = (int*)alloc(256);
  int*      cnt1  = (int*)alloc(256);
  float*    pd2   = (float*)alloc((size_t)2 * B_ * S_ * 4);        // 256 KB

  // prep
  k_prep_wih<<<(2048 * 320) / 256, 256, 0, stream>>>(w_ih_0f, w_ih_0b, Bt0, 300, 320, 2048 * 320);
  k_prep_wih<<<(2048 * 512) / 256, 256, 0, stream>>>(w_ih_1f, w_ih_1b, Bt1, 512, 512, 2048 * 512);
  k_prep_whh<<<524288 / 256, 256, 0, stream>>>(w_hh_0f, w_hh_0b, Wr0);
  k_prep_whh<<<524288 / 256, 256, 0, stream>>>(w_hh_1f, w_hh_1b, Wr1);
  k_prep_bias<<<8, 256, 0, stream>>>(b_ih_0f, b_hh_0f, b_ih_0b, b_hh_0b, bias0);
  k_prep_bias<<<8, 256, 0, stream>>>(b_ih_1f, b_hh_1f, b_ih_1b, b_hh_1b, bias1);
  k_gather<<<(T_ * 40) / 256, 256, 0, stream>>>(ids, emb, xbf);

  hipMemsetAsync(hg0, 0, (size_t)8 * 2 * 16 * 256 * 2, stream);
  hipMemsetAsync(hg1, 0, (size_t)8 * 2 * 16 * 256 * 2, stream);
  hipMemsetAsync(cnt0, 0, 256, stream);
  hipMemsetAsync(cnt1, 0, 256, stream);
  hipMemsetAsync(pd2, 0, (size_t)2 * B_ * S_ * 4, stream);
  hipMemsetAsync((char*)d_out + (size_t)T_ * 4, 0, 4, stream);

  // layer 0
  k_gemm<320><<<dim3(16, 256), 256, 0, stream>>>(xbf, Bt0, bias0, gx);
  k_rec<0><<<32, 256, 0, stream>>>(gx, Wr0, hg0, cnt0, h1bf, pd2, w_lin);

  // layer 1
  k_gemm<512><<<dim3(16, 256), 256, 0, stream>>>(h1bf, Bt1, bias1, gx);
  k_rec<1><<<32, 256, 0, stream>>>(gx, Wr1, hg1, cnt1, h1bf, pd2, w_lin);

  k_final<<<64, 256, 0, stream>>>(pd2, labels, masks, b_lin, out);
}

// Round 3
// 3359.917 us; speedup vs baseline: 2.2496x; 1.7217x over previous
//
#include <hip/hip_runtime.h>
#include <hip/hip_bf16.h>
#include <stdint.h>

// Problem constants
#define B_  64
#define S_  512
#define E_  300
#define H_  256
#define T_  (B_*S_)     // 32768 tokens
#define G4H 1024        // 4*H gate rows per direction

using half8  = __attribute__((ext_vector_type(8))) _Float16;
using half4  = __attribute__((ext_vector_type(4))) _Float16;
using float4v = __attribute__((ext_vector_type(4))) float;

union H2 { _Float16 h[2]; uint32_t u; };

__device__ inline float sigm(float x) { return 1.f / (1.f + __expf(-x)); }
__device__ inline float tanhf_(float x) {
  float cx = fminf(fmaxf(x, -15.f), 15.f);
  float e = __expf(2.f * cx);
  return (e - 1.f) / (e + 1.f);
}

// ---------------------------------------------------------------------------
// Prep kernels (unchanged)
// ---------------------------------------------------------------------------
__global__ __launch_bounds__(256) void k_prep_wih(const float* __restrict__ wf,
    const float* __restrict__ wb, _Float16* __restrict__ Bt,
    int KIN, int KP, int total)
{
  int idx = blockIdx.x * 256 + threadIdx.x;
  if (idx >= total) return;
  int n = idx / KP, k = idx % KP;
  int dd = n >> 10, nn = n & 1023;
  int row = (nn & 3) * 256 + (nn >> 2);
  const float* src = dd ? wb : wf;
  Bt[idx] = (_Float16)(k < KIN ? src[row * KIN + k] : 0.f);
}

__global__ __launch_bounds__(256) void k_prep_whh(const float* __restrict__ wf,
    const float* __restrict__ wb, _Float16* __restrict__ Wr)
{
  int idx = blockIdx.x * 256 + threadIdx.x;     // 0 .. 2*1024*256-1
  int dd = idx >> 18;
  int rem = idx & 262143;
  int n = rem >> 8, k = rem & 255;
  int row = (n & 3) * 256 + (n >> 2);
  Wr[idx] = (_Float16)((dd ? wb : wf)[row * 256 + k]);
}

__global__ void k_prep_bias(const float* __restrict__ bif, const float* __restrict__ bhf,
    const float* __restrict__ bib, const float* __restrict__ bhb, float* __restrict__ bias)
{
  int n = blockIdx.x * 256 + threadIdx.x;       // 0..2047
  int dd = n >> 10, nn = n & 1023;
  int row = (nn & 3) * 256 + (nn >> 2);
  bias[n] = dd ? (bib[row] + bhb[row]) : (bif[row] + bhf[row]);
}

__global__ __launch_bounds__(256) void k_gather(const int* __restrict__ ids,
    const float* __restrict__ emb, _Float16* __restrict__ xbf)
{
  int idx = blockIdx.x * 256 + threadIdx.x;     // T*40 threads, 8 f16 each
  int tt = idx / 40;
  int ch = idx % 40;
  int b = tt & 63, s = tt >> 6;
  int id = ids[b * S_ + s];
  const float* src = emb + (size_t)id * E_ + ch * 8;
  half8 v;
#pragma unroll
  for (int e = 0; e < 8; ++e) {
    int k = ch * 8 + e;
    v[e] = (_Float16)(k < E_ ? src[e] : 0.f);
  }
  *(half8*)(xbf + (size_t)tt * 320 + ch * 8) = v;
}

// ---------------------------------------------------------------------------
// Projection GEMM (unchanged): gx[d][t][b][n'] = A @ Bt^T + bias
// ---------------------------------------------------------------------------
template<int K>
__global__ __launch_bounds__(256) void k_gemm(const _Float16* __restrict__ A,
    const _Float16* __restrict__ Bt, const float* __restrict__ bias,
    _Float16* __restrict__ gx)
{
  __shared__ _Float16 sA[128 * 72];
  __shared__ _Float16 sB[128 * 72];
  const int tid = threadIdx.x;
  const int t0 = blockIdx.y * 128;
  const int n0 = blockIdx.x * 128;
  const int lane = tid & 63, wid = tid >> 6;
  const int l15 = lane & 15, q = lane >> 4;
  const int wm = wid & 1, wn = wid >> 1;

  float4v acc[4][4] = {};

  for (int kt = 0; kt < K / 64; ++kt) {
    __syncthreads();
#pragma unroll
    for (int c = 0; c < 4; ++c) {
      int f = tid * 4 + c;
      int row = f >> 3, seg = f & 7;
      *(half8*)&sA[row * 72 + seg * 8] =
          *(const half8*)(A + (size_t)(t0 + row) * K + kt * 64 + seg * 8);
      *(half8*)&sB[row * 72 + seg * 8] =
          *(const half8*)(Bt + (size_t)(n0 + row) * K + kt * 64 + seg * 8);
    }
    __syncthreads();
#pragma unroll
    for (int kk = 0; kk < 2; ++kk) {
      half8 a[4], b[4];
#pragma unroll
      for (int mt = 0; mt < 4; ++mt)
        a[mt] = *(const half8*)&sA[(wm * 64 + mt * 16 + l15) * 72 + kk * 32 + q * 8];
#pragma unroll
      for (int nt = 0; nt < 4; ++nt)
        b[nt] = *(const half8*)&sB[(wn * 64 + nt * 16 + l15) * 72 + kk * 32 + q * 8];
#pragma unroll
      for (int mt = 0; mt < 4; ++mt)
#pragma unroll
        for (int nt = 0; nt < 4; ++nt)
          acc[mt][nt] = __builtin_amdgcn_mfma_f32_16x16x32_f16(a[mt], b[nt], acc[mt][nt], 0, 0, 0);
    }
  }

#pragma unroll
  for (int mt = 0; mt < 4; ++mt) {
#pragma unroll
    for (int nt = 0; nt < 4; ++nt) {
      int token = t0 + wm * 64 + mt * 16 + q * 4;
      int n = n0 + wn * 64 + nt * 16 + l15;
      float bs = bias[n];
      size_t base = (size_t)(n >> 10) * ((size_t)T_ * G4H) + (size_t)token * G4H + (n & 1023);
#pragma unroll
      for (int r = 0; r < 4; ++r)
        gx[base + (size_t)r * G4H] = (_Float16)(acc[mt][nt][r] + bs);
    }
  }
}

// ---------------------------------------------------------------------------
// Persistent recurrence. Grid = 32 blocks: bx = d*16 + rg*4 + g.
// Cross-block h exchange: tag-in-word 64-bit RELAXED agent-scope atomics
// (no threadfence / no release-acquire => no L2 writeback/invalidate).
// Word = (tag=t+1)<<32 | two f16 h values. Two-slot parity ping-pong
// prevents the producer-1-step-ahead overwrite race.
// hx layout: [group 8][slot 2][word 2048], word = rg*512 + bl*32 + jpair.
// ---------------------------------------------------------------------------
template<int LAYER>
__global__ __launch_bounds__(256, 1) void k_rec(const _Float16* __restrict__ gx,
    const _Float16* __restrict__ Wr, uint64_t* __restrict__ hx,
    _Float16* __restrict__ h1bf, float* __restrict__ pd2,
    const float* __restrict__ w_lin)
{
  const int bx = blockIdx.x;
  const int d = bx >> 4, rg = (bx >> 2) & 3, g = bx & 3;
  const int tid = threadIdx.x;
  const int lane = tid & 63, wv = tid >> 6;
  const int l15 = lane & 15, q = lane >> 4;
  const int b0g = g * 16;           // global batch base
  const int n0g = rg * 256;         // gate-row base within direction

  __shared__ _Float16 hstage[16 * 288];   // h_prev [b][k], pad to 288 (16B rows)
  __shared__ float    preS[16 * 260];     // preact [b][row_local], +4 pad

  // zero hstage (h(0) = 0)
  for (int i = tid; i < 16 * 288 / 2; i += 256)
    ((uint32_t*)hstage)[i] = 0u;

  // ---- weight fragments in registers (held across t) ----
  half8 wfrag[4][8];
#pragma unroll
  for (int nt = 0; nt < 4; ++nt)
#pragma unroll
    for (int kt = 0; kt < 8; ++kt)
      wfrag[nt][kt] = *(const half8*)(Wr +
          (size_t)(d * G4H + n0g + wv * 64 + nt * 16 + l15) * H_ + kt * 32 + q * 8);

  // epilogue-role constants: thread owns 4 cells (batch bl, j = jg..jg+3)
  const int bl = tid >> 4;                  // 0..15
  const int jl4 = (tid & 15) * 4;           // local j within rg's 64
  const int bglob = b0g + bl;
  const int jg = rg * 64 + jl4;
  float wl[4];
#pragma unroll
  for (int cc = 0; cc < 4; ++cc) wl[cc] = w_lin[jg + cc];
  float creg[4] = {0.f, 0.f, 0.f, 0.f};

  uint64_t* gbase = hx + (size_t)(d * 4 + g) * 2 * 2048;

  // poll word ids for the 3 foreign quarters (2 words each)
  int pidx[6];
  {
    int c6 = 0;
#pragma unroll
    for (int qq = 1; qq <= 3; ++qq) {
      int q2 = (rg + qq) & 3;
      pidx[c6++] = q2 * 512 + tid * 2;
      pidx[c6++] = q2 * 512 + tid * 2 + 1;
    }
  }

  for (int t = 0; t < S_; ++t) {
    const int time = d ? (S_ - 1 - t) : t;

    // issue gx loads early (independent of handoff)
    const _Float16* gxp = gx + ((size_t)d * T_ + (size_t)time * B_ + bglob) * G4H
                             + n0g + (tid & 15) * 16;
    half8 gxa = *(const half8*)(gxp);
    half8 gxb = *(const half8*)(gxp + 8);

    if (t > 0) {
      // poll foreign quarters of h(t) from slot t&1, tag must equal t
      const uint64_t* slot = gbase + (size_t)(t & 1) * 2048;
      uint64_t got[6];
      unsigned pend = 0x3f;
      while (pend) {
#pragma unroll
        for (int w = 0; w < 6; ++w) {
          if (pend & (1u << w)) {
            uint64_t v = __hip_atomic_load(slot + pidx[w], __ATOMIC_RELAXED,
                                           __HIP_MEMORY_SCOPE_AGENT);
            if ((uint32_t)(v >> 32) == (uint32_t)t) { got[w] = v; pend &= ~(1u << w); }
          }
        }
      }
#pragma unroll
      for (int w = 0; w < 6; ++w) {
        int gw = pidx[w];
        int q2 = gw >> 9, loc = gw & 511;
        int sb = loc >> 5, jp = loc & 31;
        ((uint32_t*)hstage)[sb * 144 + q2 * 32 + jp] = (uint32_t)got[w];
      }
    }
    __syncthreads();   // hstage ready (covers init, own-quarter prev write, stage)

    // MFMA: pre[b 16][rows 256] = h(t) @ Wq^T
    float4v acc[4] = {};
#pragma unroll
    for (int kt = 0; kt < 8; ++kt) {
      half8 a = *(const half8*)&hstage[l15 * 288 + kt * 32 + q * 8];
#pragma unroll
      for (int nt = 0; nt < 4; ++nt)
        acc[nt] = __builtin_amdgcn_mfma_f32_16x16x32_f16(a, wfrag[nt][kt], acc[nt], 0, 0, 0);
    }

    // scatter acc -> preS  (b = q*4+r, row_local = wv*64 + nt*16 + l15)
#pragma unroll
    for (int nt = 0; nt < 4; ++nt)
#pragma unroll
      for (int r = 0; r < 4; ++r)
        preS[(q * 4 + r) * 260 + wv * 64 + nt * 16 + l15] = acc[nt][r];
    __syncthreads();

    // cell update: 4 cells per thread
    half4 hv4;
    float partial = 0.f;
#pragma unroll
    for (int cc = 0; cc < 4; ++cc) {
      float4v p = *(const float4v*)&preS[bl * 260 + (jl4 + cc) * 4];
      float gxi = (float)(cc < 2 ? gxa[cc * 4 + 0] : gxb[(cc - 2) * 4 + 0]);
      float gxf = (float)(cc < 2 ? gxa[cc * 4 + 1] : gxb[(cc - 2) * 4 + 1]);
      float gxg = (float)(cc < 2 ? gxa[cc * 4 + 2] : gxb[(cc - 2) * 4 + 2]);
      float gxo = (float)(cc < 2 ? gxa[cc * 4 + 3] : gxb[(cc - 2) * 4 + 3]);
      float gi = p[0] + gxi, gf = p[1] + gxf, gg = p[2] + gxg, go = p[3] + gxo;
      float cv = sigm(gf) * creg[cc] + sigm(gi) * tanhf_(gg);
      float hv = sigm(go) * tanhf_(cv);
      creg[cc] = cv;
      hv4[cc] = (_Float16)hv;
      if (LAYER == 1) partial += 0.5f * hv * wl[cc];
    }

    // own quarter directly into LDS for next step (8B-aligned: jl4 % 4 == 0)
    *(half4*)&hstage[bl * 288 + jg] = hv4;

    // publish to foreign blocks: 2 tagged 64-bit relaxed atomics, slot (t+1)&1
    {
      H2 p0; p0.h[0] = hv4[0]; p0.h[1] = hv4[1];
      H2 p1; p1.h[0] = hv4[2]; p1.h[1] = hv4[3];
      uint64_t tg = ((uint64_t)(uint32_t)(t + 1)) << 32;
      uint64_t* slot = gbase + (size_t)((t + 1) & 1) * 2048;
      int wb = rg * 512 + bl * 32 + (jl4 >> 1);
      __hip_atomic_store(slot + wb,     tg | p0.u, __ATOMIC_RELAXED, __HIP_MEMORY_SCOPE_AGENT);
      __hip_atomic_store(slot + wb + 1, tg | p1.u, __ATOMIC_RELAXED, __HIP_MEMORY_SCOPE_AGENT);
    }

    if (LAYER == 0) {
      *(half4*)(h1bf + ((size_t)time * B_ + bglob) * 512 + d * H_ + jg) = hv4;
    } else {
      partial += __shfl_xor(partial, 1);
      partial += __shfl_xor(partial, 2);
      partial += __shfl_xor(partial, 4);
      partial += __shfl_xor(partial, 8);
      if ((tid & 15) == 0)
        atomicAdd(pd2 + ((size_t)d * B_ + bglob) * S_ + time, partial);
    }
  }
}

// scores + masked-MSE loss
__global__ __launch_bounds__(256) void k_final(const float* __restrict__ pd2,
    const float* __restrict__ labels, const int* __restrict__ masks,
    const float* __restrict__ b_lin, float* __restrict__ out)
{
  int b = blockIdx.x;
  int tid = threadIdx.x;
  float bl = b_lin[0];
  float se = 0.f, sm = 0.f;
  for (int s = tid; s < S_; s += 256) {
    float p = pd2[(size_t)b * S_ + s] + pd2[(size_t)(B_ + b) * S_ + s];
    float sc = sigm(p + bl);
    out[b * S_ + s] = sc;
    float m = (float)masks[b * S_ + s];
    float e = sc - labels[b * S_ + s];
    se += e * e * m;
    sm += m;
  }
  for (int off = 1; off < 64; off <<= 1) {
    se += __shfl_xor(se, off);
    sm += __shfl_xor(sm, off);
  }
  __shared__ float rs[4], rm[4];
  int wid = tid >> 6;
  if ((tid & 63) == 0) { rs[wid] = se; rm[wid] = sm; }
  __syncthreads();
  if (tid == 0) {
    float te = 0.f, tm = 0.f;
    for (int w = 0; w < 4; ++w) { te += rs[w]; tm += rm[w]; }
    atomicAdd(out + T_, (te / tm) * (1.f / 64.f));
  }
}

// ---------------------------------------------------------------------------
extern "C" void kernel_launch(void* const* d_in, const int* in_sizes, int n_in,
                              void* d_out, int out_size, void* d_ws, size_t ws_size,
                              hipStream_t stream)
{
  (void)in_sizes; (void)n_in; (void)out_size; (void)ws_size;
  const int*   ids    = (const int*)d_in[0];
  const float* labels = (const float*)d_in[1];
  const int*   masks  = (const int*)d_in[2];
  const float* emb    = (const float*)d_in[3];
  const float* w_ih_0f = (const float*)d_in[4];
  const float* w_hh_0f = (const float*)d_in[5];
  const float* b_ih_0f = (const float*)d_in[6];
  const float* b_hh_0f = (const float*)d_in[7];
  const float* w_ih_0b = (const float*)d_in[8];
  const float* w_hh_0b = (const float*)d_in[9];
  const float* b_ih_0b = (const float*)d_in[10];
  const float* b_hh_0b = (const float*)d_in[11];
  const float* w_ih_1f = (const float*)d_in[12];
  const float* w_hh_1f = (const float*)d_in[13];
  const float* b_ih_1f = (const float*)d_in[14];
  const float* b_hh_1f = (const float*)d_in[15];
  const float* w_ih_1b = (const float*)d_in[16];
  const float* w_hh_1b = (const float*)d_in[17];
  const float* b_ih_1b = (const float*)d_in[18];
  const float* b_hh_1b = (const float*)d_in[19];
  const float* w_lin   = (const float*)d_in[20];
  const float* b_lin   = (const float*)d_in[21];
  float* out = (float*)d_out;

  char* ws = (char*)d_ws;
  size_t off = 0;
  auto alloc = [&](size_t bytes) -> char* {
    char* p = ws + off;
    off += (bytes + 255) & ~(size_t)255;
    return p;
  };
  _Float16* xbf   = (_Float16*)alloc((size_t)T_ * 320 * 2);        // 21 MB
  _Float16* h1bf  = (_Float16*)alloc((size_t)T_ * 512 * 2);        // 33.5 MB
  _Float16* gx    = (_Float16*)alloc((size_t)2 * T_ * G4H * 2);    // 134 MB
  _Float16* Bt0   = (_Float16*)alloc((size_t)2048 * 320 * 2);
  _Float16* Bt1   = (_Float16*)alloc((size_t)2048 * 512 * 2);
  _Float16* Wr0   = (_Float16*)alloc((size_t)2 * G4H * H_ * 2);
  _Float16* Wr1   = (_Float16*)alloc((size_t)2 * G4H * H_ * 2);
  float*    bias0 = (float*)alloc(2048 * 4);
  float*    bias1 = (float*)alloc(2048 * 4);
  uint64_t* hx0   = (uint64_t*)alloc((size_t)8 * 2 * 2048 * 8);    // 256 KB
  uint64_t* hx1   = (uint64_t*)alloc((size_t)8 * 2 * 2048 * 8);    // 256 KB
  float*    pd2   = (float*)alloc((size_t)2 * B_ * S_ * 4);        // 256 KB

  // prep
  k_prep_wih<<<(2048 * 320) / 256, 256, 0, stream>>>(w_ih_0f, w_ih_0b, Bt0, 300, 320, 2048 * 320);
  k_prep_wih<<<(2048 * 512) / 256, 256, 0, stream>>>(w_ih_1f, w_ih_1b, Bt1, 512, 512, 2048 * 512);
  k_prep_whh<<<524288 / 256, 256, 0, stream>>>(w_hh_0f, w_hh_0b, Wr0);
  k_prep_whh<<<524288 / 256, 256, 0, stream>>>(w_hh_1f, w_hh_1b, Wr1);
  k_prep_bias<<<8, 256, 0, stream>>>(b_ih_0f, b_hh_0f, b_ih_0b, b_hh_0b, bias0);
  k_prep_bias<<<8, 256, 0, stream>>>(b_ih_1f, b_hh_1f, b_ih_1b, b_hh_1b, bias1);
  k_gather<<<(T_ * 40) / 256, 256, 0, stream>>>(ids, emb, xbf);

  hipMemsetAsync(hx0, 0, (size_t)8 * 2 * 2048 * 8, stream);
  hipMemsetAsync(hx1, 0, (size_t)8 * 2 * 2048 * 8, stream);
  hipMemsetAsync(pd2, 0, (size_t)2 * B_ * S_ * 4, stream);
  hipMemsetAsync((char*)d_out + (size_t)T_ * 4, 0, 4, stream);

  // layer 0
  k_gemm<320><<<dim3(16, 256), 256, 0, stream>>>(xbf, Bt0, bias0, gx);
  k_rec<0><<<32, 256, 0, stream>>>(gx, Wr0, hx0, h1bf, pd2, w_lin);

  // layer 1
  k_gemm<512><<<dim3(16, 256), 256, 0, stream>>>(h1bf, Bt1, bias1, gx);
  k_rec<1><<<32, 256, 0, stream>>>(gx, Wr1, hx1, h1bf, pd2, w_lin);

  k_final<<<64, 256, 0, stream>>>(pd2, labels, masks, b_lin, out);
}